// Round 2
// baseline (75.556 us; speedup 1.0000x reference)
//
#include <hip/hip_runtime.h>

// LogSig_var: depth-2 log-signature over 64 segments of ragged paths.
// inp:    (256, 2048, 12) fp32
// length: (256,) int32, 1..2048
// out:    (256, 64, 78) fp32   [12 increments + 66 Levy areas (i<j lex order)]
//
// Per-segment algebra (segments independent, no cumsum needed):
//   inc_i  = Xb_i - Xa_i
//   levy_p = 0.5*( sum_{t=a}^{b-1} [X_i(t)X_j(t+1) - X_j(t)X_i(t+1)]
//                  - (Xa_i*Xb_j - Xa_j*Xb_i) )
//
// R6: occupancy experiment. R5 (DPP reduce + 2-deep pipeline) was dead
// neutral -> kernel is latency-bound at 1 wave/SIMD, not issue-bound.
// R2/R3's evidence against wide lane splits was DS-reduction cost
// (528/4224/10560 DS-instr/CU -> 75/82/100us); DPP changed that tradeoff:
// 8 lanes/seg with {2 DPP levels + 1 shfl_xor(4)} costs 66 DS/thread x 8
// waves = 528 wave-DS-ops/CU == the R1 optimum's DS budget, while
//   (a) halving each lane's trip count, and
//   (b) doubling waves/SIMD to 2 -> one wave's 132-FMA block covers the
//       other wave's cold-HBM vmcnt stall (L3 flushed by harness poison).
// __launch_bounds__(512,2) caps VGPR at 256 (est ~160) so the full 8-wave
// block stays resident.

#define BATCH 256
#define TLEN 2048
#define DCH 12
#define NSEG 64
#define NPAIR 66          // d*(d-1)/2
#define NCH 78            // 12 + 66
#define LPS 8             // lanes per segment

__device__ __forceinline__ int tv_round(int j, int Lf) {
    // round-half-even(1 + j*Lf/64), exact. q = j*Lf <= 64*2047 < 2^17.
    int q = j * Lf;
    int base = 1 + (q >> 6);
    int r = q & 63;
    int up = (r > 32) || (r == 32 && (base & 1));
    return base + up;
}

__device__ __forceinline__ void load_row(const float* __restrict__ X, int r,
                                         float* __restrict__ v) {
    const float4* p = (const float4*)(X + r * DCH);
    float4 f0 = p[0], f1 = p[1], f2 = p[2];
    v[0] = f0.x; v[1] = f0.y; v[2]  = f0.z; v[3]  = f0.w;
    v[4] = f1.x; v[5] = f1.y; v[6]  = f1.z; v[7]  = f1.w;
    v[8] = f2.x; v[9] = f2.y; v[10] = f2.z; v[11] = f2.w;
}

__device__ __forceinline__ void load_pair(const float* __restrict__ X, int t,
                                          bool expand, int k, int Lm1,
                                          float (&x)[DCH], float (&y)[DCH]) {
    int r0, r1;
    if (expand) {
        r0 = min(t / k, Lm1);
        r1 = min((t + 1) / k, Lm1);
    } else {
        r0 = t;
        r1 = t + 1;
    }
    load_row(X, r0, x);
    load_row(X, r1, y);
}

// 132 FMAs, ordered SLP-friendly for v_pk_fma_f32 (consecutive acc[p],
// shared x[i] / y[i] multiplier).
__device__ __forceinline__ void accum_step(const float (&x)[DCH],
                                           const float (&y)[DCH],
                                           float (&acc)[NPAIR]) {
    int p = 0;
#pragma unroll
    for (int i = 0; i < DCH - 1; ++i)
#pragma unroll
        for (int jj = i + 1; jj < DCH; ++jj) {
            acc[p] = fmaf(x[i], y[jj], acc[p]);
            ++p;
        }
    p = 0;
#pragma unroll
    for (int i = 0; i < DCH - 1; ++i)
#pragma unroll
        for (int jj = i + 1; jj < DCH; ++jj) {
            acc[p] = fmaf(-x[jj], y[i], acc[p]);
            ++p;
        }
}

// 8-lane butterfly: xor-1 and xor-2 via DPP quad_perm on the VALU pipe
// (zero DS ops), xor-4 via one ds_swizzle-backed shuffle. All 8 lanes of
// the group end up holding the full sum.
__device__ __forceinline__ float group8_reduce_add(float v) {
    float s1 = __int_as_float(__builtin_amdgcn_update_dpp(
        0, __float_as_int(v), 0xB1, 0xF, 0xF, true));   // quad_perm [1,0,3,2]
    v += s1;
    float s2 = __int_as_float(__builtin_amdgcn_update_dpp(
        0, __float_as_int(v), 0x4E, 0xF, 0xF, true));   // quad_perm [2,3,0,1]
    v += s2;
    v += __shfl_xor(v, 4, 64);                          // one DS op
    return v;
}

__global__ __launch_bounds__(512, 2) void logsig_kernel(
        const float* __restrict__ inp,
        const int* __restrict__ length,
        float* __restrict__ out) {
    __shared__ __align__(16) float lds_out[NSEG * NCH];  // 19968 B

    const int batch = blockIdx.x;
    const int tid = threadIdx.x;
    const int L = length[batch];
    const int Lm1 = L - 1;

    const float* __restrict__ X = inp + (size_t)batch * TLEN * DCH;

    // ---- segment assignment: 8 contiguous lanes per segment ----
    const int lane = tid & 63;
    const int wave = tid >> 6;
    const int seg = wave * 8 + (lane >> 3);   // 8 waves x 8 segs = 64
    const int q8 = lane & (LPS - 1);

    const bool expand = (L < NSEG + 1);
    const int k = expand ? (NSEG / L + 1) : 1;
    const int Leff = expand ? k * L : L;
    const int Lf = Leff - 1;

    const int a = tv_round(seg, Lf) - 1;
    const int b = tv_round(seg + 1, Lf) - 1;

    float acc[NPAIR];
#pragma unroll
    for (int p = 0; p < NPAIR; ++p) acc[p] = 0.0f;

    // ---- preload 2 pipeline stages (A: t, B: t+LPS) ----
    float xA[DCH], yA[DCH], xB[DCH], yB[DCH];
    int t = a + q8;
    if (t < b) load_pair(X, t, expand, k, Lm1, xA, yA);
    if (t + LPS < b) load_pair(X, t + LPS, expand, k, Lm1, xB, yB);

    // ---- boundary rows, issued early: latency hides under the main loop ----
    float xa[DCH], xb[DCH];
    {
        int ra, rb;
        if (expand) {
            ra = min(a / k, Lm1);
            rb = min(b / k, Lm1);
        } else {
            ra = a;
            rb = b;
        }
        load_row(X, ra, xa);
        load_row(X, rb, xb);
    }

    // ---- unroll-by-2 double-buffered main loop (no rotation movs) ----
    while (t < b) {
        accum_step(xA, yA, acc);                              // consume A(t)
        if (t + 2 * LPS < b) load_pair(X, t + 2 * LPS, expand, k, Lm1, xA, yA);
        t += LPS;
        if (t >= b) break;
        accum_step(xB, yB, acc);                              // consume B(t)
        if (t + 2 * LPS < b) load_pair(X, t + 2 * LPS, expand, k, Lm1, xB, yB);
        t += LPS;
    }

    // ---- reduce the 8 lanes of each segment (2 DPP levels + 1 shfl) ----
#pragma unroll
    for (int p = 0; p < NPAIR; ++p) acc[p] = group8_reduce_add(acc[p]);

    // ---- writer lane: boundary term + store channels to LDS ----
    if (q8 == 0) {
        float* o = lds_out + seg * NCH;
#pragma unroll
        for (int i = 0; i < DCH; ++i) o[i] = xb[i] - xa[i];
        int p = 0;
#pragma unroll
        for (int i = 0; i < DCH - 1; ++i)
#pragma unroll
            for (int jj = i + 1; jj < DCH; ++jj) {
                o[DCH + p] = 0.5f * (acc[p] - (xa[i] * xb[jj] - xa[jj] * xb[i]));
                ++p;
            }
    }
    __syncthreads();

    // ---- coalesced copy-out: 64*78 = 4992 floats = 1248 float4 ----
    {
        float4* od = (float4*)(out + (size_t)batch * NSEG * NCH);
        const float4* os = (const float4*)lds_out;
        for (int i = tid; i < (NSEG * NCH) / 4; i += 512) od[i] = os[i];
    }
}

extern "C" void kernel_launch(void* const* d_in, const int* in_sizes, int n_in,
                              void* d_out, int out_size, void* d_ws, size_t ws_size,
                              hipStream_t stream) {
    const float* inp = (const float*)d_in[0];
    const int* length = (const int*)d_in[1];
    float* out = (float*)d_out;
    logsig_kernel<<<BATCH, 512, 0, stream>>>(inp, length, out);
}

// Round 3
// 72.773 us; speedup vs baseline: 1.0382x; 1.0382x over previous
//
#include <hip/hip_runtime.h>

// LogSig_var: depth-2 log-signature over 64 segments of ragged paths.
// inp:    (256, 2048, 12) fp32
// length: (256,) int32, 1..2048
// out:    (256, 64, 78) fp32   [12 increments + 66 Levy areas (i<j lex order)]
//
// Per-segment algebra (segments independent, no cumsum needed):
//   inc_i  = Xb_i - Xa_i
//   levy_p = 0.5*( sum_{t=a}^{b-1} [X_i(t)X_j(t+1) - X_j(t)X_i(t+1)]
//                  - (Xa_i*Xb_j - Xa_j*Xb_i) )
//
// R7: revert to R5 (best measured: 73.63 us). Session evidence:
//  - R5 (DPP reduce, -130 instr/thread): neutral vs R4 (73.68 -> 73.63).
//  - R6 (8 lanes/seg, 512 thr, 2 waves/SIMD): +1.9 us regression —
//    reintroduced 66 DS-shuffle ops/thread (vs R5's zero-DS pure-DPP
//    reduction) and halved per-lane compute, so nothing left to hide
//    latency with.
//  - In all rounds the top-5 rocprof dispatches are the harness' 268MB
//    poison fills (43-47 us @ 72-78% HBM peak); the kernel itself never
//    appears (< 43 us, arithmetic says single-digit us). The measured
//    dur_us is dominated by the un-controllable reset floor.
// Config: 1 block/batch, 256 thr, 4 lanes/seg, pure-DPP quad reduction,
// 2-deep double-buffered main loop, boundary rows hoisted above the loop.

#define BATCH 256
#define TLEN 2048
#define DCH 12
#define NSEG 64
#define NPAIR 66          // d*(d-1)/2
#define NCH 78            // 12 + 66

__device__ __forceinline__ int tv_round(int j, int Lf) {
    // round-half-even(1 + j*Lf/64), exact. q = j*Lf <= 64*2047 < 2^17.
    int q = j * Lf;
    int base = 1 + (q >> 6);
    int r = q & 63;
    int up = (r > 32) || (r == 32 && (base & 1));
    return base + up;
}

__device__ __forceinline__ void load_row(const float* __restrict__ X, int r,
                                         float* __restrict__ v) {
    const float4* p = (const float4*)(X + r * DCH);
    float4 f0 = p[0], f1 = p[1], f2 = p[2];
    v[0] = f0.x; v[1] = f0.y; v[2]  = f0.z; v[3]  = f0.w;
    v[4] = f1.x; v[5] = f1.y; v[6]  = f1.z; v[7]  = f1.w;
    v[8] = f2.x; v[9] = f2.y; v[10] = f2.z; v[11] = f2.w;
}

__device__ __forceinline__ void load_pair(const float* __restrict__ X, int t,
                                          bool expand, int k, int Lm1,
                                          float (&x)[DCH], float (&y)[DCH]) {
    int r0, r1;
    if (expand) {
        r0 = min(t / k, Lm1);
        r1 = min((t + 1) / k, Lm1);
    } else {
        r0 = t;
        r1 = t + 1;
    }
    load_row(X, r0, x);
    load_row(X, r1, y);
}

// 132 FMAs, ordered SLP-friendly for v_pk_fma_f32 (consecutive acc[p],
// shared x[i] / y[i] multiplier).
__device__ __forceinline__ void accum_step(const float (&x)[DCH],
                                           const float (&y)[DCH],
                                           float (&acc)[NPAIR]) {
    int p = 0;
#pragma unroll
    for (int i = 0; i < DCH - 1; ++i)
#pragma unroll
        for (int jj = i + 1; jj < DCH; ++jj) {
            acc[p] = fmaf(x[i], y[jj], acc[p]);
            ++p;
        }
    p = 0;
#pragma unroll
    for (int i = 0; i < DCH - 1; ++i)
#pragma unroll
        for (int jj = i + 1; jj < DCH; ++jj) {
            acc[p] = fmaf(-x[jj], y[i], acc[p]);
            ++p;
        }
}

// quad-butterfly add via DPP (VALU pipe, no DS ops). All 4 lanes of the
// quad end up holding the full sum.
__device__ __forceinline__ float quad_reduce_add(float v) {
    float s1 = __int_as_float(__builtin_amdgcn_update_dpp(
        0, __float_as_int(v), 0xB1, 0xF, 0xF, true));   // quad_perm [1,0,3,2]
    v += s1;
    float s2 = __int_as_float(__builtin_amdgcn_update_dpp(
        0, __float_as_int(v), 0x4E, 0xF, 0xF, true));   // quad_perm [2,3,0,1]
    return v + s2;
}

__global__ __launch_bounds__(256) void logsig_kernel(
        const float* __restrict__ inp,
        const int* __restrict__ length,
        float* __restrict__ out) {
    __shared__ __align__(16) float lds_out[NSEG * NCH];  // 19968 B

    const int batch = blockIdx.x;
    const int tid = threadIdx.x;
    const int L = length[batch];
    const int Lm1 = L - 1;

    const float* __restrict__ X = inp + (size_t)batch * TLEN * DCH;

    // ---- segment assignment: 4 contiguous lanes per segment ----
    const int lane = tid & 63;
    const int wave = tid >> 6;
    const int seg = wave * 16 + (lane >> 2);
    const int q4 = lane & 3;

    const bool expand = (L < NSEG + 1);
    const int k = expand ? (NSEG / L + 1) : 1;
    const int Leff = expand ? k * L : L;
    const int Lf = Leff - 1;

    const int a = tv_round(seg, Lf) - 1;
    const int b = tv_round(seg + 1, Lf) - 1;

    float acc[NPAIR];
#pragma unroll
    for (int p = 0; p < NPAIR; ++p) acc[p] = 0.0f;

    // ---- preload 2 pipeline stages (A: t, B: t+4) ----
    float xA[DCH], yA[DCH], xB[DCH], yB[DCH];
    int t = a + q4;
    if (t < b) load_pair(X, t, expand, k, Lm1, xA, yA);
    if (t + 4 < b) load_pair(X, t + 4, expand, k, Lm1, xB, yB);

    // ---- boundary rows, issued early: latency hides under the main loop ----
    float xa[DCH], xb[DCH];
    {
        int ra, rb;
        if (expand) {
            ra = min(a / k, Lm1);
            rb = min(b / k, Lm1);
        } else {
            ra = a;
            rb = b;
        }
        load_row(X, ra, xa);
        load_row(X, rb, xb);
    }

    // ---- unroll-by-2 double-buffered main loop (no rotation movs) ----
    while (t < b) {
        accum_step(xA, yA, acc);                              // consume A(t)
        if (t + 8 < b) load_pair(X, t + 8, expand, k, Lm1, xA, yA);
        t += 4;
        if (t >= b) break;
        accum_step(xB, yB, acc);                              // consume B(t)
        if (t + 8 < b) load_pair(X, t + 8, expand, k, Lm1, xB, yB);
        t += 4;
    }

    // ---- reduce the 4 lanes of each segment on the VALU pipe (DPP) ----
#pragma unroll
    for (int p = 0; p < NPAIR; ++p) acc[p] = quad_reduce_add(acc[p]);

    // ---- writer lane: boundary term + store channels to LDS ----
    if (q4 == 0) {
        float* o = lds_out + seg * NCH;
#pragma unroll
        for (int i = 0; i < DCH; ++i) o[i] = xb[i] - xa[i];
        int p = 0;
#pragma unroll
        for (int i = 0; i < DCH - 1; ++i)
#pragma unroll
            for (int jj = i + 1; jj < DCH; ++jj) {
                o[DCH + p] = 0.5f * (acc[p] - (xa[i] * xb[jj] - xa[jj] * xb[i]));
                ++p;
            }
    }
    __syncthreads();

    // ---- coalesced copy-out: 64*78 = 4992 floats = 1248 float4 ----
    {
        float4* od = (float4*)(out + (size_t)batch * NSEG * NCH);
        const float4* os = (const float4*)lds_out;
        for (int i = tid; i < (NSEG * NCH) / 4; i += 256) od[i] = os[i];
    }
}

extern "C" void kernel_launch(void* const* d_in, const int* in_sizes, int n_in,
                              void* d_out, int out_size, void* d_ws, size_t ws_size,
                              hipStream_t stream) {
    const float* inp = (const float*)d_in[0];
    const int* length = (const int*)d_in[1];
    float* out = (float*)d_out;
    logsig_kernel<<<BATCH, 256, 0, stream>>>(inp, length, out);
}